// Round 9
// baseline (1924.967 us; speedup 1.0000x reference)
//
#include <hip/hip_runtime.h>
#include <hip/hip_bf16.h>
#include <math.h>

typedef float f32x4 __attribute__((ext_vector_type(4)));
typedef __bf16 bf16x8 __attribute__((ext_vector_type(8)));
typedef unsigned short u16x4 __attribute__((ext_vector_type(4)));

union U64 { unsigned long long u; u16x4 v; };
union U128 { unsigned long long q[2]; bf16x8 b; };

// ---------------- LDS (32768 B -> 5 blocks/CU) ----------------
// SA [64 tok][192 ch] bf16 stride 384 XOR((r&7)<<4)   : 24576
// K  [64 tok][32 kch] tok-paired 128B rows            : 4096
// VT [32 vch][64 tok] stride 128 XOR((r&7)<<4)        : 4096
// G (MLP, overlays K+VT) [64 tok][64 mch] stride 128  : 8192
#define SA_B 0
#define K_B  24576
#define VT_B 28672
#define G_B  24576
#define SMEM 32768

__device__ __forceinline__ int sa_off(int row,int byt){ return SA_B + row*384 + (byt ^ ((row&7)<<4)); }
__device__ __forceinline__ int k_off (int tok,int byt){ return K_B + (tok>>1)*128 + (tok&1)*64 + (byt ^ (((tok>>1)&3)<<4)); }
__device__ __forceinline__ int vt_off(int row,int byt){ return VT_B + row*128 + (byt ^ ((row&7)<<4)); }
__device__ __forceinline__ int g_off (int row,int byt){ return G_B  + row*128 + (byt ^ ((row&7)<<4)); }
__device__ __forceinline__ unsigned short f2b(float x){ return __builtin_bit_cast(unsigned short, (__bf16)x); }
__device__ __forceinline__ float b2f(unsigned short u){ return (float)__builtin_bit_cast(__bf16, u); }

// pair-shuffle: build MFMA A/B fragment (k=8*lg..+7, col=l16) from two packed D-tiles
__device__ __forceinline__ bf16x8 frag32(unsigned long long t0, unsigned long long t1,
                                         int lg, int l16){
  const int sA = ((lg&1)<<5) + l16;
  unsigned long long a0=__shfl(t0,sA), b0=__shfl(t0,sA+16);
  unsigned long long a1=__shfl(t1,sA), b1=__shfl(t1,sA+16);
  U128 u; u.q[0]=(lg<2)?a0:a1; u.q[1]=(lg<2)?b0:b1;
  return u.b;
}
__device__ __forceinline__ unsigned long long pack4(f32x4 a){
  U64 u;
  #pragma unroll
  for(int r=0;r<4;++r) u.v[r]=f2b(a[r]);
  return u.u;
}

// Transpose + cast weights to bf16 [N][K]
__global__ void prep_weights(const float* __restrict__ wqkv, const float* __restrict__ wproj,
                             const float* __restrict__ wmlp1, const float* __restrict__ wmlp2,
                             unsigned short* __restrict__ ws){
  int idx = blockIdx.x*256 + threadIdx.x;
  if (idx < 110592){ int n=idx/192, k=idx%192; ws[idx] = f2b(wqkv[k*576+n]); }
  else if (idx < 147456){ int i=idx-110592; int n=i/192, k=i%192; ws[idx] = f2b(wproj[k*192+n]); }
  else if (idx < 294912){ int i=idx-147456; int n=i/192, k=i%192; ws[idx] = f2b(wmlp1[k*768+n]); }
  else if (idx < 442368){ int i=idx-294912; int n=i/768, k=i%768; ws[idx] = f2b(wmlp2[k*192+n]); }
}

// xwh layout (bf16): elem idx = ((win*48 + g)*64 + tok)*4 + e   (g = ch/4)
__global__ void relayout_in(const float* __restrict__ x, unsigned short* __restrict__ xwh){
  const int w = threadIdx.x, bh = blockIdx.x, b = bh>>8, h = bh&255;
  const int win = b*1024 + (h>>3)*32 + (w>>3);
  const int tok = (h&7)*8 + (w&7);
  const size_t src = (size_t)b*192*65536 + (size_t)h*256 + w;
  #pragma unroll 1
  for(int c0=0;c0<192;c0+=32){
    float buf[32];
    #pragma unroll
    for(int j=0;j<32;++j) buf[j] = x[src + (size_t)(c0+j)*65536];
    #pragma unroll
    for(int j4=0;j4<8;++j4){
      u16x4 pk;
      #pragma unroll
      for(int r=0;r<4;++r) pk[r]=f2b(buf[j4*4+r]);
      *(u16x4*)(xwh + ((size_t)(win*48 + c0/4 + j4)*64 + tok)*4) = pk;
    }
  }
}

__global__ void relayout_out(const unsigned short* __restrict__ rwh, float* __restrict__ out){
  const int w = threadIdx.x, bh = blockIdx.x, b = bh>>8, h = bh&255;
  const int win = b*1024 + (h>>3)*32 + (w>>3);
  const int tok = (h&7)*8 + (w&7);
  const size_t dst = (size_t)b*192*65536 + (size_t)h*256 + w;
  #pragma unroll 1
  for(int c0=0;c0<192;c0+=32){
    u16x4 buf[8];
    #pragma unroll
    for(int j4=0;j4<8;++j4) buf[j4] = *(const u16x4*)(rwh + ((size_t)(win*48 + c0/4 + j4)*64 + tok)*4);
    #pragma unroll
    for(int j=0;j<32;++j) out[dst + (size_t)(c0+j)*65536] = b2f(buf[j>>2][j&3]);
  }
}

// K2: thread(w,lg,l16) owns tok=16w+l16, ch {16mt+4lg+r, mt 0..11}. 32KB LDS, 5 blocks/CU.
template<int DIRECT>
__global__ void __launch_bounds__(256, 5) winblock(
    const void* xin_, void* outp_,
    const float* __restrict__ bqkv, const float* __restrict__ bproj,
    const float* __restrict__ ln1g, const float* __restrict__ ln1b,
    const float* __restrict__ ln2g, const float* __restrict__ ln2b,
    const float* __restrict__ bmlp1, const float* __restrict__ bmlp2,
    const unsigned short* __restrict__ wqkvT, const unsigned short* __restrict__ wprojT,
    const unsigned short* __restrict__ wmlp1T, const unsigned short* __restrict__ wmlp2T)
{
  __shared__ __align__(16) char sm[SMEM];
  const int tid=threadIdx.x, w=tid>>6, lg=(tid>>4)&3, l16=tid&15;
  const int wid=blockIdx.x;
  const int tok = 16*w + l16;

  // ---- residual t[12]: ch 16mt+4lg+r, own tok ----
  f32x4 t[12];
  if(DIRECT){
    const float* xin=(const float*)xin_;
    const int bb=wid>>10, wh=(wid>>5)&31, wwi=wid&31;
    const size_t imgoff=(size_t)bb*192*65536 + (size_t)(wh*8)*256 + (size_t)(wwi*8);
    const int tp=(tok>>3)*256+(tok&7);
    #pragma unroll
    for(int mt=0;mt<12;++mt)
      #pragma unroll
      for(int r=0;r<4;++r)
        t[mt][r]=xin[imgoff+(size_t)(16*mt+4*lg+r)*65536+tp];
  } else {
    const unsigned short* xwh=(const unsigned short*)xin_;
    #pragma unroll
    for(int mt=0;mt<12;++mt){
      const u16x4 v=*(const u16x4*)(xwh + ((size_t)(wid*48 + 4*mt+lg)*64 + tok)*4);
      #pragma unroll
      for(int r=0;r<4;++r) t[mt][r]=b2f(v[r]);
    }
  }

  // ---- shuffle-only LayerNorm -> SA own row ----
  auto lnorm=[&](const float* gg,const float* bbv){
    float s=0.f,s2=0.f;
    #pragma unroll
    for(int mt=0;mt<12;++mt){
      #pragma unroll
      for(int r=0;r<4;++r){ s+=t[mt][r]; s2+=t[mt][r]*t[mt][r]; }
    }
    s+=__shfl_xor(s,16); s+=__shfl_xor(s,32);
    s2+=__shfl_xor(s2,16); s2+=__shfl_xor(s2,32);
    const float mean=s*(1.f/192.f);
    const float rstd=rsqrtf(s2*(1.f/192.f)-mean*mean+1e-5f);
    #pragma unroll
    for(int mt=0;mt<12;++mt){
      const f32x4 g4=*(const f32x4*)(gg+16*mt+4*lg);
      const f32x4 b4=*(const f32x4*)(bbv+16*mt+4*lg);
      u16x4 pk;
      #pragma unroll
      for(int r=0;r<4;++r) pk[r]=f2b((t[mt][r]-mean)*rstd*g4[r]+b4[r]);
      *(u16x4*)(sm+sa_off(tok,(16*mt+4*lg)*2))=pk;
    }
  };

  lnorm(ln1g, ln1b);
  __syncthreads();   // h visible

  // ---- c1: Q tok-major (own toks, regs); K,V ch-major split (ct,tbase) -> LDS ----
  const int ct=w>>1, tb=2*(w&1);
  unsigned long long q0,q1;
  auto c1=[&](int hh){
    f32x4 qa0={0,0,0,0},qa1={0,0,0,0},ka0={0,0,0,0},ka1={0,0,0,0},va0={0,0,0,0},va1={0,0,0,0};
    #pragma unroll
    for(int ks=0;ks<6;++ks){
      const int ko=ks*32+lg*8, bo=ks*64+lg*16;
      const bf16x8 hQ =*(const bf16x8*)(sm+sa_off(tok, bo));
      const bf16x8 hk0=*(const bf16x8*)(sm+sa_off(16*tb+l16, bo));
      const bf16x8 hk1=*(const bf16x8*)(sm+sa_off(16*(tb+1)+l16, bo));
      const bf16x8 awq0=*(const bf16x8*)(wqkvT+(      hh*32   +l16)*192+ko);
      const bf16x8 awq1=*(const bf16x8*)(wqkvT+(      hh*32+16+l16)*192+ko);
      const bf16x8 awk =*(const bf16x8*)(wqkvT+(192 + hh*32+ct*16+l16)*192+ko);
      const bf16x8 bwv =*(const bf16x8*)(wqkvT+(384 + hh*32+ct*16+l16)*192+ko);
      qa0=__builtin_amdgcn_mfma_f32_16x16x32_bf16(awq0,hQ ,qa0,0,0,0);  // D[qch][own tok]
      qa1=__builtin_amdgcn_mfma_f32_16x16x32_bf16(awq1,hQ ,qa1,0,0,0);
      ka0=__builtin_amdgcn_mfma_f32_16x16x32_bf16(awk ,hk0,ka0,0,0,0);  // D[kch ct][tok tb+j]
      ka1=__builtin_amdgcn_mfma_f32_16x16x32_bf16(awk ,hk1,ka1,0,0,0);
      va0=__builtin_amdgcn_mfma_f32_16x16x32_bf16(hk0 ,bwv,va0,0,0,0);  // D[tok tb+j][vch ct]
      va1=__builtin_amdgcn_mfma_f32_16x16x32_bf16(hk1 ,bwv,va1,0,0,0);
    }
    {
      const f32x4 b0=*(const f32x4*)(bqkv+          4*lg + hh*32);
      const f32x4 b1=*(const f32x4*)(bqkv+     16 + 4*lg + hh*32);
      q0=pack4(qa0+b0); q1=pack4(qa1+b1);
    }
    {
      const f32x4 kb=*(const f32x4*)(bqkv+192+hh*32+ct*16+4*lg);
      U64 u0,u1;
      #pragma unroll
      for(int r=0;r<4;++r){ u0.v[r]=f2b(ka0[r]+kb[r]); u1.v[r]=f2b(ka1[r]+kb[r]); }
      *(u16x4*)(sm+k_off(16*tb    +l16, ct*32+8*lg))=u0.v;   // K[tok][kch]
      *(u16x4*)(sm+k_off(16*(tb+1)+l16, ct*32+8*lg))=u1.v;
    }
    {
      const float bv=bqkv[384+hh*32+ct*16+l16];
      U64 u0,u1;
      #pragma unroll
      for(int r=0;r<4;++r){ u0.v[r]=f2b(va0[r]+bv); u1.v[r]=f2b(va1[r]+bv); }
      *(u16x4*)(sm+vt_off(ct*16+l16,(16*tb    +4*lg)*2))=u0.v;  // VT[vch][tok]
      *(u16x4*)(sm+vt_off(ct*16+l16,(16*(tb+1)+4*lg)*2))=u1.v;
    }
  };

  c1(0);
  __syncthreads();

  const float SM_C = 0.25503487f;  // log2(e)/sqrt(32)
  #pragma unroll 1
  for(int h=0;h<6;++h){
    bf16x8 of;
    {
      // S^T = K.Q (A=K LDS rows ktok, B=Q reg-frag col=own q)
      const bf16x8 qf=frag32(q0,q1,lg,l16);
      f32x4 sv[4];
      #pragma unroll
      for(int kt=0;kt<4;++kt){
        const bf16x8 akf=*(const bf16x8*)(sm+k_off(16*kt+l16,lg*16));
        sv[kt]=__builtin_amdgcn_mfma_f32_16x16x32_bf16(akf,qf,(f32x4){0,0,0,0},0,0,0);
      }
      float mx=-3.0e38f;
      #pragma unroll
      for(int kt=0;kt<4;++kt){
        #pragma unroll
        for(int r=0;r<4;++r) mx=fmaxf(mx,sv[kt][r]);
      }
      mx=fmaxf(mx,__shfl_xor(mx,16)); mx=fmaxf(mx,__shfl_xor(mx,32));
      float sum=0.f;
      #pragma unroll
      for(int kt=0;kt<4;++kt){
        #pragma unroll
        for(int r=0;r<4;++r){ float e=exp2f((sv[kt][r]-mx)*SM_C); sv[kt][r]=e; sum+=e; }
      }
      sum+=__shfl_xor(sum,16); sum+=__shfl_xor(sum,32);
      const float rs=1.f/sum;
      U64 pk0,pk1,pk2,pk3;
      #pragma unroll
      for(int r=0;r<4;++r){ pk0.v[r]=f2b(sv[0][r]*rs); pk1.v[r]=f2b(sv[1][r]*rs);
                            pk2.v[r]=f2b(sv[2][r]*rs); pk3.v[r]=f2b(sv[3][r]*rs); }
      const int srcA = ((lg&1)<<5) + l16, srcB = srcA + 16;
      unsigned long long rA0=__shfl(pk0.u,srcA), rB0=__shfl(pk0.u,srcB);
      unsigned long long rA1=__shfl(pk1.u,srcA), rB1=__shfl(pk1.u,srcB);
      unsigned long long rA2=__shfl(pk2.u,srcA), rB2=__shfl(pk2.u,srcB);
      unsigned long long rA3=__shfl(pk3.u,srcA), rB3=__shfl(pk3.u,srcB);
      U128 pf0, pf1;
      pf0.q[0]=(lg<2)?rA0:rA1;  pf0.q[1]=(lg<2)?rB0:rB1;   // ktok 0..31
      pf1.q[0]=(lg<2)?rA2:rA3;  pf1.q[1]=(lg<2)?rB2:rB3;   // ktok 32..63
      // PV: A=VT rows d, B=P col=own q -> D[d][own q]
      f32x4 ov0={0,0,0,0},ov1={0,0,0,0};
      const bf16x8 a00=*(const bf16x8*)(sm+vt_off(   l16,   lg*16));
      const bf16x8 a01=*(const bf16x8*)(sm+vt_off(   l16,64+lg*16));
      const bf16x8 a10=*(const bf16x8*)(sm+vt_off(16+l16,   lg*16));
      const bf16x8 a11=*(const bf16x8*)(sm+vt_off(16+l16,64+lg*16));
      ov0=__builtin_amdgcn_mfma_f32_16x16x32_bf16(a00,pf0.b,ov0,0,0,0);
      ov0=__builtin_amdgcn_mfma_f32_16x16x32_bf16(a01,pf1.b,ov0,0,0,0);
      ov1=__builtin_amdgcn_mfma_f32_16x16x32_bf16(a10,pf0.b,ov1,0,0,0);
      ov1=__builtin_amdgcn_mfma_f32_16x16x32_bf16(a11,pf1.b,ov1,0,0,0);
      of = frag32(pack4(ov0),pack4(ov1),lg,l16);   // k=d, col=own q (in-register O)
    }
    __syncthreads();   // K(h),VT(h) reads done -> safe to overwrite
    if(h<5) c1(h+1);
    // proj accumulate into t (A=Wproj all 12 ch-tiles, B=O-frag)
    #pragma unroll
    for(int mt=0;mt<12;++mt){
      const bf16x8 aw=*(const bf16x8*)(wprojT+(16*mt+l16)*192+h*32+lg*8);
      t[mt]=__builtin_amdgcn_mfma_f32_16x16x32_bf16(aw,of,t[mt],0,0,0);
    }
    if(h<5) __syncthreads();   // K,VT(h+1) visible
  }

  // ---- proj bias; LN2 -> SA ----
  #pragma unroll
  for(int mt=0;mt<12;++mt) t[mt]+=*(const f32x4*)(bproj+16*mt+4*lg);
  lnorm(ln2g, ln2b);
  __syncthreads();   // h2 visible (K/VT dead -> G area free)

  // ---- MLP: 12 chunks of 64 mch; G overlays K/VT; MLP2 accumulates into t ----
  #pragma unroll 1
  for(int qc=0;qc<12;++qc){
    f32x4 g4[4];
    #pragma unroll
    for(int tt=0;tt<4;++tt) g4[tt]=(f32x4){0,0,0,0};
    #pragma unroll
    for(int ks=0;ks<6;++ks){
      const bf16x8 aw1=*(const bf16x8*)(wmlp1T+(qc*64+16*w+l16)*192+ks*32+lg*8);
      #pragma unroll
      for(int tt=0;tt<4;++tt){
        const bf16x8 bh2=*(const bf16x8*)(sm+sa_off(16*tt+l16,ks*64+lg*16));
        g4[tt]=__builtin_amdgcn_mfma_f32_16x16x32_bf16(aw1,bh2,g4[tt],0,0,0);
      }
    }
    const f32x4 b1=*(const f32x4*)(bmlp1+qc*64+16*w+4*lg);
    #pragma unroll
    for(int tt=0;tt<4;++tt){
      u16x4 pg;
      #pragma unroll
      for(int r=0;r<4;++r){
        const float xv=g4[tt][r]+b1[r];
        pg[r]=f2b(0.5f*xv*(1.f+erff(xv*0.70710678118654752f)));
      }
      *(u16x4*)(sm+g_off(16*tt+l16, 32*w+8*lg))=pg;   // G[tok][mch-local]
    }
    __syncthreads();   // G visible
    #pragma unroll
    for(int ks2=0;ks2<2;++ks2){
      const bf16x8 bg=*(const bf16x8*)(sm+g_off(tok, 64*ks2+16*lg));  // own tok row
      #pragma unroll
      for(int mt=0;mt<12;++mt){
        const bf16x8 aw2=*(const bf16x8*)(wmlp2T+(16*mt+l16)*768+qc*64+ks2*32+lg*8);
        t[mt]=__builtin_amdgcn_mfma_f32_16x16x32_bf16(aw2,bg,t[mt],0,0,0);
      }
    }
    if(qc<11) __syncthreads();   // WAR before next G write
  }

  // ---- epilogue: out = t + bmlp2 ----
  if(DIRECT){
    float* outp=(float*)outp_;
    const int bb=wid>>10, wh=(wid>>5)&31, wwi=wid&31;
    const size_t imgoff=(size_t)bb*192*65536 + (size_t)(wh*8)*256 + (size_t)(wwi*8);
    const int tp=(tok>>3)*256+(tok&7);
    #pragma unroll
    for(int mt=0;mt<12;++mt){
      const f32x4 b2=*(const f32x4*)(bmlp2+16*mt+4*lg);
      #pragma unroll
      for(int r=0;r<4;++r)
        outp[imgoff+(size_t)(16*mt+4*lg+r)*65536+tp]=t[mt][r]+b2[r];
    }
  } else {
    unsigned short* rwh=(unsigned short*)outp_;
    #pragma unroll
    for(int mt=0;mt<12;++mt){
      const f32x4 b2=*(const f32x4*)(bmlp2+16*mt+4*lg);
      u16x4 po;
      #pragma unroll
      for(int r=0;r<4;++r) po[r]=f2b(t[mt][r]+b2[r]);
      *(u16x4*)(rwh + ((size_t)(wid*48 + 4*mt+lg)*64 + tok)*4)=po;
    }
  }
}

extern "C" void kernel_launch(void* const* d_in, const int* in_sizes, int n_in,
                              void* d_out, int out_size, void* d_ws, size_t ws_size,
                              hipStream_t stream) {
  const float* x      = (const float*)d_in[0];
  const float* w_qkv  = (const float*)d_in[1];
  const float* b_qkv  = (const float*)d_in[2];
  const float* w_proj = (const float*)d_in[3];
  const float* b_proj = (const float*)d_in[4];
  const float* ln1g   = (const float*)d_in[5];
  const float* ln1b   = (const float*)d_in[6];
  const float* ln2g   = (const float*)d_in[7];
  const float* ln2b   = (const float*)d_in[8];
  const float* w_mlp1 = (const float*)d_in[9];
  const float* b_mlp1 = (const float*)d_in[10];
  const float* w_mlp2 = (const float*)d_in[11];
  const float* b_mlp2 = (const float*)d_in[12];
  float* out = (float*)d_out;

  const size_t XWH_BYTES = 4096ull*12288ull*2ull;   // 100,663,296 (bf16 windowized act)
  const size_t W_PAD     = 1ull<<20;

  unsigned short* wsu = (unsigned short*)d_ws;
  prep_weights<<<dim3(1728), dim3(256), 0, stream>>>(w_qkv, w_proj, w_mlp1, w_mlp2, wsu);

  if (ws_size >= W_PAD + XWH_BYTES){
    unsigned short* xwh = (unsigned short*)((char*)d_ws + W_PAD);
    relayout_in<<<dim3(1024), dim3(256), 0, stream>>>(x, xwh);
    winblock<0><<<dim3(4096), dim3(256), 0, stream>>>(
        (const void*)xwh, (void*)xwh, b_qkv, b_proj, ln1g, ln1b, ln2g, ln2b, b_mlp1, b_mlp2,
        wsu, wsu+110592, wsu+147456, wsu+294912);
    relayout_out<<<dim3(1024), dim3(256), 0, stream>>>(xwh, out);
  } else {
    winblock<1><<<dim3(4096), dim3(256), 0, stream>>>(
        (const void*)x, (void*)out, b_qkv, b_proj, ln1g, ln1b, ln2g, ln2b, b_mlp1, b_mlp2,
        wsu, wsu+110592, wsu+147456, wsu+294912);
  }
}

// Round 10
// 891.742 us; speedup vs baseline: 2.1587x; 2.1587x over previous
//
#include <hip/hip_runtime.h>
#include <hip/hip_bf16.h>
#include <math.h>

typedef float f32x4 __attribute__((ext_vector_type(4)));
typedef float f32x2 __attribute__((ext_vector_type(2)));
typedef __bf16 bf16x8 __attribute__((ext_vector_type(8)));
typedef unsigned short u16x4 __attribute__((ext_vector_type(4)));

// ---------------- LDS map (40960 B exactly -> 4 blocks/CU) ----------------
#define SA_B  0
#define RQ_B  24576
#define RK_B  28672
#define RVT_B 32768
#define RO_B  36864
#define RG_B  24576
#define SMEM  40960

__device__ __forceinline__ int sa_off(int row,int byte){ return SA_B + row*384 + (byte ^ ((row&7)<<4)); }
__device__ __forceinline__ int vt_off(int row,int byte){ return RVT_B+ row*128 + (byte ^ ((row&7)<<4)); }
__device__ __forceinline__ int g_off (int row,int byte){ return RG_B + row*256 + (byte ^ ((row&7)<<4)); }
__device__ __forceinline__ int qp_off(int base,int tok,int byte){
  return base + (tok>>1)*128 + (tok&1)*64 + (byte ^ (((tok>>1)&3)<<4));
}
__device__ __forceinline__ unsigned short f2b(float x){ return __builtin_bit_cast(unsigned short, (__bf16)x); }

union U64 { unsigned long long u; u16x4 v; };
union U128 { unsigned long long q[2]; bf16x8 b; };

// Transpose + cast weights to bf16 [N][K]
__global__ void prep_weights(const float* __restrict__ wqkv, const float* __restrict__ wproj,
                             const float* __restrict__ wmlp1, const float* __restrict__ wmlp2,
                             unsigned short* __restrict__ ws){
  int idx = blockIdx.x*256 + threadIdx.x;
  if (idx < 110592){ int n=idx/192, k=idx%192; ws[idx] = f2b(wqkv[k*576+n]); }
  else if (idx < 147456){ int i=idx-110592; int n=i/192, k=i%192; ws[idx] = f2b(wproj[k*192+n]); }
  else if (idx < 294912){ int i=idx-147456; int n=i/192, k=i%192; ws[idx] = f2b(wmlp1[k*768+n]); }
  else if (idx < 442368){ int i=idx-294912; int n=i/768, k=i%768; ws[idx] = f2b(wmlp2[k*192+n]); }
}

// K2. Thread (w,lg,l16): owns toks {16tt+l16} x chs {48w+16mt+4lg+r}. 40KB LDS.
// Quad-XCD-affine remap: the 4 windows sharing each 128B x/out line run on ONE XCD
// so their 32B partial-line accesses merge in that XCD's L2.
__global__ void __launch_bounds__(256, 4) winblock(
    const float* __restrict__ xin, float* __restrict__ outp,
    const float* __restrict__ bqkv, const float* __restrict__ bproj,
    const float* __restrict__ ln1g, const float* __restrict__ ln1b,
    const float* __restrict__ ln2g, const float* __restrict__ ln2b,
    const float* __restrict__ bmlp1, const float* __restrict__ bmlp2,
    const unsigned short* __restrict__ wqkvT, const unsigned short* __restrict__ wprojT,
    const unsigned short* __restrict__ wmlp1T, const unsigned short* __restrict__ wmlp2T)
{
  __shared__ __align__(16) char sm[SMEM];
  const int tid=threadIdx.x, w=tid>>6, lg=(tid>>4)&3, l16=tid&15;
  // ---- XCD-affine window id: b -> (xcd=b&7, m=b>>3); wid = ((m>>2)*8+xcd)*4 + (m&3)
  const int b_=blockIdx.x;
  const int wid = ((((b_>>3)>>2)*8 + (b_&7))<<2) + ((b_>>3)&3);
  const int bb=wid>>10, wh=(wid>>5)&31, wwi=wid&31;
  const size_t imgoff=(size_t)bb*192*65536 + (size_t)(wh*8)*256 + (size_t)(wwi*8);
  f32x2* red = (f32x2*)(sm + RQ_B);

  // ---- residual t[mt][tt]: ch 48w+16mt+4lg+r, tok 16tt+l16 ----
  f32x4 t[3][4];
  #pragma unroll
  for(int mt=0;mt<3;++mt)
    #pragma unroll
    for(int tt=0;tt<4;++tt){
      const int T=16*tt+l16, tp=(T>>3)*256+(T&7);
      #pragma unroll
      for(int r=0;r<4;++r)
        t[mt][tt][r]=xin[imgoff+(size_t)(48*w+16*mt+4*lg+r)*65536+tp];
    }

  // ---- LayerNorm -> bf16 into SA (contains one internal barrier) ----
  auto layernorm = [&](const float* gg, const float* bbv){
    float s[4], s2[4];
    #pragma unroll
    for(int tt=0;tt<4;++tt){
      float a=0.f,b2=0.f;
      #pragma unroll
      for(int mt=0;mt<3;++mt){
        #pragma unroll
        for(int r=0;r<4;++r){ a+=t[mt][tt][r]; b2+=t[mt][tt][r]*t[mt][tt][r]; }
      }
      a+=__shfl_xor(a,16); a+=__shfl_xor(a,32);
      b2+=__shfl_xor(b2,16); b2+=__shfl_xor(b2,32);
      s[tt]=a; s2[tt]=b2;
    }
    if(lg==0) red[w*64 +  0+l16]=(f32x2){s[0],s2[0]};
    if(lg==1) red[w*64 + 16+l16]=(f32x2){s[1],s2[1]};
    if(lg==2) red[w*64 + 32+l16]=(f32x2){s[2],s2[2]};
    if(lg==3) red[w*64 + 48+l16]=(f32x2){s[3],s2[3]};
    __syncthreads();
    float mean[4], rstd[4];
    #pragma unroll
    for(int tt=0;tt<4;++tt){
      float S=0.f,S2=0.f;
      #pragma unroll
      for(int w2=0;w2<4;++w2){ f32x2 v=red[w2*64+16*tt+l16]; S+=v.x; S2+=v.y; }
      mean[tt]=S*(1.f/192.f);
      rstd[tt]=rsqrtf(S2*(1.f/192.f)-mean[tt]*mean[tt]+1e-5f);
    }
    #pragma unroll
    for(int mt=0;mt<3;++mt){
      const f32x4 g4=*(const f32x4*)(gg+48*w+16*mt+4*lg);
      const f32x4 b4=*(const f32x4*)(bbv+48*w+16*mt+4*lg);
      #pragma unroll
      for(int tt=0;tt<4;++tt){
        u16x4 pk;
        #pragma unroll
        for(int r=0;r<4;++r) pk[r]=f2b((t[mt][tt][r]-mean[tt])*rstd[tt]*g4[r]+b4[r]);
        *(u16x4*)(sm+sa_off(16*tt+l16,(48*w+16*mt+4*lg)*2))=pk;
      }
    }
  };

  layernorm(ln1g, ln1b);
  __syncthreads();   // h visible

  // ---- QKV producer: wave w -> ct=w>>1 (ch-half of head), tok-tiles {2(w&1),+1} ----
  const int ct=w>>1, tbase=2*(w&1);
  auto c1=[&](int hh){
    f32x4 qa[2],ka[2],va[2];
    #pragma unroll
    for(int i=0;i<2;++i){ qa[i]=(f32x4){0,0,0,0}; ka[i]=(f32x4){0,0,0,0}; va[i]=(f32x4){0,0,0,0}; }
    #pragma unroll
    for(int ks=0;ks<6;++ks){
      bf16x8 hfrag[2];
      #pragma unroll
      for(int i=0;i<2;++i) hfrag[i]=*(const bf16x8*)(sm+sa_off(16*(tbase+i)+l16, ks*64+lg*16));
      const bf16x8 awq=*(const bf16x8*)(wqkvT+(      hh*32+ct*16+l16)*192+ks*32+lg*8);
      const bf16x8 awk=*(const bf16x8*)(wqkvT+(192 + hh*32+ct*16+l16)*192+ks*32+lg*8);
      const bf16x8 bwv=*(const bf16x8*)(wqkvT+(384 + hh*32+ct*16+l16)*192+ks*32+lg*8);
      #pragma unroll
      for(int i=0;i<2;++i){
        qa[i]=__builtin_amdgcn_mfma_f32_16x16x32_bf16(awq,hfrag[i],qa[i],0,0,0);  // D[qch][tok]
        ka[i]=__builtin_amdgcn_mfma_f32_16x16x32_bf16(awk,hfrag[i],ka[i],0,0,0);
        va[i]=__builtin_amdgcn_mfma_f32_16x16x32_bf16(hfrag[i],bwv,va[i],0,0,0);  // D[tok][vch]
      }
    }
    const f32x4 bq4=*(const f32x4*)(bqkv+      hh*32+ct*16+4*lg);
    const f32x4 bk4=*(const f32x4*)(bqkv+192 + hh*32+ct*16+4*lg);
    const float bv =bqkv[384 + hh*32+ct*16+l16];
    #pragma unroll
    for(int i=0;i<2;++i){
      const int tok=16*(tbase+i)+l16;
      u16x4 pq,pk,pv;
      #pragma unroll
      for(int r=0;r<4;++r){
        pq[r]=f2b(qa[i][r]+bq4[r]);
        pk[r]=f2b(ka[i][r]+bk4[r]);
        pv[r]=f2b(va[i][r]+bv);
      }
      *(u16x4*)(sm+qp_off(RQ_B,tok,32*ct+8*lg))=pq;                  // Q[tok][qch]
      *(u16x4*)(sm+qp_off(RK_B,tok,32*ct+8*lg))=pk;                  // K[tok][qch]
      *(u16x4*)(sm+vt_off(ct*16+l16,(16*(tbase+i)+4*lg)*2))=pv;      // VT[vch][tok]
    }
  };

  c1(0);
  __syncthreads();

  const float SM_C = 0.25503487f;  // log2(e)/sqrt(32), applied in f32 at exp2
  #pragma unroll 1
  for(int h=0;h<6;++h){
    // ---- S^T = K.Q (A=K rows=ktok, B=Q col=own q) ; softmax in-register ----
    {
      const int q=16*w+l16;
      const bf16x8 bqf=*(const bf16x8*)(sm+qp_off(RQ_B,q,lg*16));
      f32x4 sv[4];
      #pragma unroll
      for(int kt=0;kt<4;++kt){
        const bf16x8 akf=*(const bf16x8*)(sm+qp_off(RK_B,16*kt+l16,lg*16));
        sv[kt]=__builtin_amdgcn_mfma_f32_16x16x32_bf16(akf,bqf,(f32x4){0,0,0,0},0,0,0);
      }
      float mx=-3.0e38f;
      #pragma unroll
      for(int kt=0;kt<4;++kt){
        #pragma unroll
        for(int r=0;r<4;++r) mx=fmaxf(mx,sv[kt][r]);
      }
      mx=fmaxf(mx,__shfl_xor(mx,16)); mx=fmaxf(mx,__shfl_xor(mx,32));
      float sum=0.f;
      #pragma unroll
      for(int kt=0;kt<4;++kt){
        #pragma unroll
        for(int r=0;r<4;++r){ float e=exp2f((sv[kt][r]-mx)*SM_C); sv[kt][r]=e; sum+=e; }
      }
      sum+=__shfl_xor(sum,16); sum+=__shfl_xor(sum,32);
      const float rs=1.f/sum;
      U64 pk0,pk1,pk2,pk3;
      #pragma unroll
      for(int r=0;r<4;++r){ pk0.v[r]=f2b(sv[0][r]*rs); pk1.v[r]=f2b(sv[1][r]*rs);
                            pk2.v[r]=f2b(sv[2][r]*rs); pk3.v[r]=f2b(sv[3][r]*rs); }
      const int srcA = ((lg&1)<<5) + l16, srcB = srcA + 16;
      unsigned long long rA0=__shfl(pk0.u,srcA), rB0=__shfl(pk0.u,srcB);
      unsigned long long rA1=__shfl(pk1.u,srcA), rB1=__shfl(pk1.u,srcB);
      unsigned long long rA2=__shfl(pk2.u,srcA), rB2=__shfl(pk2.u,srcB);
      unsigned long long rA3=__shfl(pk3.u,srcA), rB3=__shfl(pk3.u,srcB);
      U128 pf0, pf1;
      pf0.q[0]=(lg<2)?rA0:rA1;  pf0.q[1]=(lg<2)?rB0:rB1;   // ktok 0..31
      pf1.q[0]=(lg<2)?rA2:rA3;  pf1.q[1]=(lg<2)?rB2:rB3;   // ktok 32..63
      // ---- PV: A=VT (rows d), B=P (col=own q) -> D[d][q]; write O[q][d] ----
      f32x4 ov[2]={(f32x4){0,0,0,0},(f32x4){0,0,0,0}};
      #pragma unroll
      for(int dt=0;dt<2;++dt){
        const bf16x8 av0=*(const bf16x8*)(sm+vt_off(16*dt+l16,lg*16));
        const bf16x8 av1=*(const bf16x8*)(sm+vt_off(16*dt+l16,64+lg*16));
        ov[dt]=__builtin_amdgcn_mfma_f32_16x16x32_bf16(av0,pf0.b,ov[dt],0,0,0);
        ov[dt]=__builtin_amdgcn_mfma_f32_16x16x32_bf16(av1,pf1.b,ov[dt],0,0,0);
      }
      #pragma unroll
      for(int dt=0;dt<2;++dt){
        u16x4 po;
        #pragma unroll
        for(int r=0;r<4;++r) po[r]=f2b(ov[dt][r]);
        *(u16x4*)(sm+qp_off(RO_B,q,32*dt+8*lg))=po;   // own q row
      }
    }
    __syncthreads();   // O visible; Q/K/VT reads done
    // ---- proj accumulate directly into t: A=Wproj rows=own outch, B=O col=tok ----
    {
      bf16x8 bo[4];
      #pragma unroll
      for(int tt=0;tt<4;++tt) bo[tt]=*(const bf16x8*)(sm+qp_off(RO_B,16*tt+l16,lg*16));
      #pragma unroll
      for(int mt=0;mt<3;++mt){
        const bf16x8 aw=*(const bf16x8*)(wprojT+(16*(3*w+mt)+l16)*192+h*32+lg*8);
        #pragma unroll
        for(int tt=0;tt<4;++tt)
          t[mt][tt]=__builtin_amdgcn_mfma_f32_16x16x32_bf16(aw,bo[tt],t[mt][tt],0,0,0);
      }
    }
    if(h<5){ c1(h+1); __syncthreads(); }
  }

  // ---- proj bias once ----
  #pragma unroll
  for(int mt=0;mt<3;++mt){
    const f32x4 bp=*(const f32x4*)(bproj+48*w+16*mt+4*lg);
    #pragma unroll
    for(int tt=0;tt<4;++tt) t[mt][tt]+=bp;
  }

  // ---- LN2 (red overlays RQ; all Q reads finished) ----
  layernorm(ln2g, ln2b);
  __syncthreads();   // h2 visible; attn buffers dead -> G area free

  // ---- MLP: 6 chunks of 128 mch; MLP2 accumulates into t ----
  #pragma unroll 1
  for(int qc=0;qc<6;++qc){
    f32x4 g[2][4];
    #pragma unroll
    for(int m=0;m<2;++m)
      #pragma unroll
      for(int tt=0;tt<4;++tt) g[m][tt]=(f32x4){0,0,0,0};
    #pragma unroll
    for(int ks=0;ks<6;++ks){
      bf16x8 bh2[4];
      #pragma unroll
      for(int tt=0;tt<4;++tt) bh2[tt]=*(const bf16x8*)(sm+sa_off(16*tt+l16,ks*64+lg*16));
      #pragma unroll
      for(int m=0;m<2;++m){
        const bf16x8 aw=*(const bf16x8*)(wmlp1T+(qc*128+16*(2*w+m)+l16)*192+ks*32+lg*8);
        #pragma unroll
        for(int tt=0;tt<4;++tt)
          g[m][tt]=__builtin_amdgcn_mfma_f32_16x16x32_bf16(aw,bh2[tt],g[m][tt],0,0,0);
      }
    }
    #pragma unroll
    for(int m=0;m<2;++m){
      const f32x4 b1=*(const f32x4*)(bmlp1+qc*128+16*(2*w+m)+4*lg);
      #pragma unroll
      for(int tt=0;tt<4;++tt){
        u16x4 pg;
        #pragma unroll
        for(int r=0;r<4;++r){
          const float xv=g[m][tt][r]+b1[r];
          pg[r]=f2b(0.5f*xv*(1.f+erff(xv*0.70710678118654752f)));
        }
        *(u16x4*)(sm+g_off(16*tt+l16,(16*(2*w+m)+4*lg)*2))=pg;  // G[tok][mch]
      }
    }
    __syncthreads();   // G visible
    #pragma unroll
    for(int ks2=0;ks2<4;++ks2){
      bf16x8 bg[4];
      #pragma unroll
      for(int tt=0;tt<4;++tt) bg[tt]=*(const bf16x8*)(sm+g_off(16*tt+l16,ks2*64+lg*16));
      #pragma unroll
      for(int mt=0;mt<3;++mt){
        const bf16x8 aw2=*(const bf16x8*)(wmlp2T+(16*(3*w+mt)+l16)*768+qc*128+ks2*32+lg*8);
        #pragma unroll
        for(int tt=0;tt<4;++tt)
          t[mt][tt]=__builtin_amdgcn_mfma_f32_16x16x32_bf16(aw2,bg[tt],t[mt][tt],0,0,0);
      }
    }
    if(qc<5) __syncthreads();  // WAR before next G write
  }

  // ---- Final: out = t + bmlp2 ----
  #pragma unroll
  for(int mt=0;mt<3;++mt){
    const f32x4 b2=*(const f32x4*)(bmlp2+48*w+16*mt+4*lg);
    #pragma unroll
    for(int tt=0;tt<4;++tt){
      const int T=16*tt+l16, tp=(T>>3)*256+(T&7);
      #pragma unroll
      for(int r=0;r<4;++r)
        outp[imgoff+(size_t)(48*w+16*mt+4*lg+r)*65536+tp]=t[mt][tt][r]+b2[r];
    }
  }
}

extern "C" void kernel_launch(void* const* d_in, const int* in_sizes, int n_in,
                              void* d_out, int out_size, void* d_ws, size_t ws_size,
                              hipStream_t stream) {
  const float* x      = (const float*)d_in[0];
  const float* w_qkv  = (const float*)d_in[1];
  const float* b_qkv  = (const float*)d_in[2];
  const float* w_proj = (const float*)d_in[3];
  const float* b_proj = (const float*)d_in[4];
  const float* ln1g   = (const float*)d_in[5];
  const float* ln1b   = (const float*)d_in[6];
  const float* ln2g   = (const float*)d_in[7];
  const float* ln2b   = (const float*)d_in[8];
  const float* w_mlp1 = (const float*)d_in[9];
  const float* b_mlp1 = (const float*)d_in[10];
  const float* w_mlp2 = (const float*)d_in[11];
  const float* b_mlp2 = (const float*)d_in[12];
  float* out = (float*)d_out;
  unsigned short* wsu = (unsigned short*)d_ws;

  prep_weights<<<dim3(1728), dim3(256), 0, stream>>>(w_qkv, w_proj, w_mlp1, w_mlp2, wsu);
  winblock<<<dim3(4096), dim3(256), 0, stream>>>(
      x, out, b_qkv, b_proj, ln1g, ln1b, ln2g, ln2b, b_mlp1, b_mlp2,
      wsu, wsu+110592, wsu+147456, wsu+294912);
}

// Round 11
// 816.095 us; speedup vs baseline: 2.3588x; 1.0927x over previous
//
#include <hip/hip_runtime.h>
#include <hip/hip_bf16.h>
#include <math.h>

typedef float f32x4 __attribute__((ext_vector_type(4)));
typedef float f32x2 __attribute__((ext_vector_type(2)));
typedef __bf16 bf16x8 __attribute__((ext_vector_type(8)));
typedef unsigned short u16x4 __attribute__((ext_vector_type(4)));

// ---------------- LDS map (40960 B exactly -> 4 blocks/CU) ----------------
#define SA_B  0
#define RQ_B  24576
#define RK_B  28672
#define RVT_B 32768
#define RO_B  36864
#define RG_B  24576
#define SMEM  40960

__device__ __forceinline__ int sa_off(int row,int byte){ return SA_B + row*384 + (byte ^ ((row&7)<<4)); }
__device__ __forceinline__ int vt_off(int row,int byte){ return RVT_B+ row*128 + (byte ^ ((row&7)<<4)); }
__device__ __forceinline__ int g_off (int row,int byte){ return RG_B + row*256 + (byte ^ ((row&7)<<4)); }
__device__ __forceinline__ int qp_off(int base,int tok,int byte){
  return base + (tok>>1)*128 + (tok&1)*64 + (byte ^ (((tok>>1)&3)<<4));
}
__device__ __forceinline__ unsigned short f2b(float x){ return __builtin_bit_cast(unsigned short, (__bf16)x); }
__device__ __forceinline__ float b2f(unsigned short u){ return (float)__builtin_bit_cast(__bf16, u); }

union U64 { unsigned long long u; u16x4 v; };
union U128 { unsigned long long q[2]; bf16x8 b; };

// Transpose + cast weights to bf16 [N][K]
__global__ void prep_weights(const float* __restrict__ wqkv, const float* __restrict__ wproj,
                             const float* __restrict__ wmlp1, const float* __restrict__ wmlp2,
                             unsigned short* __restrict__ ws){
  int idx = blockIdx.x*256 + threadIdx.x;
  if (idx < 110592){ int n=idx/192, k=idx%192; ws[idx] = f2b(wqkv[k*576+n]); }
  else if (idx < 147456){ int i=idx-110592; int n=i/192, k=i%192; ws[idx] = f2b(wproj[k*192+n]); }
  else if (idx < 294912){ int i=idx-147456; int n=i/192, k=i%192; ws[idx] = f2b(wmlp1[k*768+n]); }
  else if (idx < 442368){ int i=idx-294912; int n=i/768, k=i%768; ws[idx] = f2b(wmlp2[k*192+n]); }
}

// xwh (bf16) chunk layout: elem = ((lw*48 + g)*64 + tok)*4 + e, ch = 4g+e, lw = local window
// K1: x[B,C,H,W] -> xwh for window-rows [r0, r0+nr). blockIdx in [0, nr*8)
__global__ void relayout_in(const float* __restrict__ x, unsigned short* __restrict__ xwh, int r0){
  const int w = threadIdx.x, i = blockIdx.x;
  const int gr = r0 + (i>>3);                 // global window-row (0..127)
  const int bb = gr>>5, hh = (gr&31)*8 + (i&7);
  const int lw = (i>>3)*32 + (w>>3);          // local window within chunk
  const int tok = (hh&7)*8 + (w&7);
  const size_t src = (size_t)bb*192*65536 + (size_t)hh*256 + w;
  #pragma unroll 1
  for(int c0=0;c0<192;c0+=32){
    float buf[32];
    #pragma unroll
    for(int j=0;j<32;++j) buf[j] = x[src + (size_t)(c0+j)*65536];
    #pragma unroll
    for(int j4=0;j4<8;++j4){
      u16x4 pk;
      #pragma unroll
      for(int r=0;r<4;++r) pk[r]=f2b(buf[j4*4+r]);
      *(u16x4*)(xwh + ((size_t)(lw*48 + c0/4 + j4)*64 + tok)*4) = pk;
    }
  }
}

// K3: xwh chunk -> out[B,C,H,W]
__global__ void relayout_out(const unsigned short* __restrict__ rwh, float* __restrict__ out, int r0){
  const int w = threadIdx.x, i = blockIdx.x;
  const int gr = r0 + (i>>3);
  const int bb = gr>>5, hh = (gr&31)*8 + (i&7);
  const int lw = (i>>3)*32 + (w>>3);
  const int tok = (hh&7)*8 + (w&7);
  const size_t dst = (size_t)bb*192*65536 + (size_t)hh*256 + w;
  #pragma unroll 1
  for(int c0=0;c0<192;c0+=32){
    u16x4 buf[8];
    #pragma unroll
    for(int j4=0;j4<8;++j4) buf[j4] = *(const u16x4*)(rwh + ((size_t)(lw*48 + c0/4 + j4)*64 + tok)*4);
    #pragma unroll
    for(int j=0;j<32;++j) out[dst + (size_t)(c0+j)*65536] = b2f(buf[j>>2][j&3]);
  }
}

// K2. Thread (w,lg,l16): owns toks {16tt+l16} x chs {48w+16mt+4lg+r}. 40KB LDS.
// MODE 1 = DIRECT (f32 strided global), MODE 2 = STAGED (bf16 xwh chunk, in-place)
template<int MODE>
__global__ void __launch_bounds__(256, 4) winblock(
    const void* xin_, void* outp_,
    const float* __restrict__ bqkv, const float* __restrict__ bproj,
    const float* __restrict__ ln1g, const float* __restrict__ ln1b,
    const float* __restrict__ ln2g, const float* __restrict__ ln2b,
    const float* __restrict__ bmlp1, const float* __restrict__ bmlp2,
    const unsigned short* __restrict__ wqkvT, const unsigned short* __restrict__ wprojT,
    const unsigned short* __restrict__ wmlp1T, const unsigned short* __restrict__ wmlp2T)
{
  __shared__ __align__(16) char sm[SMEM];
  const int tid=threadIdx.x, w=tid>>6, lg=(tid>>4)&3, l16=tid&15;
  const int wid=blockIdx.x;   // DIRECT: global window; STAGED: local window in chunk
  f32x2* red = (f32x2*)(sm + RQ_B);

  // ---- residual t[mt][tt]: ch 48w+16mt+4lg+r, tok 16tt+l16 ----
  f32x4 t[3][4];
  if(MODE==1){
    const float* xin=(const float*)xin_;
    const int bb=wid>>10, wh=(wid>>5)&31, wwi=wid&31;
    const size_t imgoff=(size_t)bb*192*65536 + (size_t)(wh*8)*256 + (size_t)(wwi*8);
    #pragma unroll
    for(int mt=0;mt<3;++mt)
      #pragma unroll
      for(int tt=0;tt<4;++tt){
        const int T=16*tt+l16, tp=(T>>3)*256+(T&7);
        #pragma unroll
        for(int r=0;r<4;++r)
          t[mt][tt][r]=xin[imgoff+(size_t)(48*w+16*mt+4*lg+r)*65536+tp];
      }
  } else {
    const unsigned short* xwh=(const unsigned short*)xin_;
    #pragma unroll
    for(int mt=0;mt<3;++mt)
      #pragma unroll
      for(int tt=0;tt<4;++tt){
        const u16x4 v=*(const u16x4*)(xwh + ((size_t)(wid*48 + 12*w+4*mt+lg)*64 + 16*tt+l16)*4);
        #pragma unroll
        for(int r=0;r<4;++r) t[mt][tt][r]=b2f(v[r]);
      }
  }

  // ---- LayerNorm -> bf16 into SA (contains one internal barrier) ----
  auto layernorm = [&](const float* gg, const float* bbv){
    float s[4], s2[4];
    #pragma unroll
    for(int tt=0;tt<4;++tt){
      float a=0.f,b2=0.f;
      #pragma unroll
      for(int mt=0;mt<3;++mt){
        #pragma unroll
        for(int r=0;r<4;++r){ a+=t[mt][tt][r]; b2+=t[mt][tt][r]*t[mt][tt][r]; }
      }
      a+=__shfl_xor(a,16); a+=__shfl_xor(a,32);
      b2+=__shfl_xor(b2,16); b2+=__shfl_xor(b2,32);
      s[tt]=a; s2[tt]=b2;
    }
    if(lg==0) red[w*64 +  0+l16]=(f32x2){s[0],s2[0]};
    if(lg==1) red[w*64 + 16+l16]=(f32x2){s[1],s2[1]};
    if(lg==2) red[w*64 + 32+l16]=(f32x2){s[2],s2[2]};
    if(lg==3) red[w*64 + 48+l16]=(f32x2){s[3],s2[3]};
    __syncthreads();
    float mean[4], rstd[4];
    #pragma unroll
    for(int tt=0;tt<4;++tt){
      float S=0.f,S2=0.f;
      #pragma unroll
      for(int w2=0;w2<4;++w2){ f32x2 v=red[w2*64+16*tt+l16]; S+=v.x; S2+=v.y; }
      mean[tt]=S*(1.f/192.f);
      rstd[tt]=rsqrtf(S2*(1.f/192.f)-mean[tt]*mean[tt]+1e-5f);
    }
    #pragma unroll
    for(int mt=0;mt<3;++mt){
      const f32x4 g4=*(const f32x4*)(gg+48*w+16*mt+4*lg);
      const f32x4 b4=*(const f32x4*)(bbv+48*w+16*mt+4*lg);
      #pragma unroll
      for(int tt=0;tt<4;++tt){
        u16x4 pk;
        #pragma unroll
        for(int r=0;r<4;++r) pk[r]=f2b((t[mt][tt][r]-mean[tt])*rstd[tt]*g4[r]+b4[r]);
        *(u16x4*)(sm+sa_off(16*tt+l16,(48*w+16*mt+4*lg)*2))=pk;
      }
    }
  };

  layernorm(ln1g, ln1b);
  __syncthreads();   // h visible

  // ---- QKV producer: wave w -> ct=w>>1 (ch-half of head), tok-tiles {2(w&1),+1} ----
  const int ct=w>>1, tbase=2*(w&1);
  auto c1=[&](int hh){
    f32x4 qa[2],ka[2],va[2];
    #pragma unroll
    for(int i=0;i<2;++i){ qa[i]=(f32x4){0,0,0,0}; ka[i]=(f32x4){0,0,0,0}; va[i]=(f32x4){0,0,0,0}; }
    #pragma unroll
    for(int ks=0;ks<6;++ks){
      bf16x8 hfrag[2];
      #pragma unroll
      for(int i=0;i<2;++i) hfrag[i]=*(const bf16x8*)(sm+sa_off(16*(tbase+i)+l16, ks*64+lg*16));
      const bf16x8 awq=*(const bf16x8*)(wqkvT+(      hh*32+ct*16+l16)*192+ks*32+lg*8);
      const bf16x8 awk=*(const bf16x8*)(wqkvT+(192 + hh*32+ct*16+l16)*192+ks*32+lg*8);
      const bf16x8 bwv=*(const bf16x8*)(wqkvT+(384 + hh*32+ct*16+l16)*192+ks*32+lg*8);
      #pragma unroll
      for(int i=0;i<2;++i){
        qa[i]=__builtin_amdgcn_mfma_f32_16x16x32_bf16(awq,hfrag[i],qa[i],0,0,0);  // D[qch][tok]
        ka[i]=__builtin_amdgcn_mfma_f32_16x16x32_bf16(awk,hfrag[i],ka[i],0,0,0);
        va[i]=__builtin_amdgcn_mfma_f32_16x16x32_bf16(hfrag[i],bwv,va[i],0,0,0);  // D[tok][vch]
      }
    }
    const f32x4 bq4=*(const f32x4*)(bqkv+      hh*32+ct*16+4*lg);
    const f32x4 bk4=*(const f32x4*)(bqkv+192 + hh*32+ct*16+4*lg);
    const float bv =bqkv[384 + hh*32+ct*16+l16];
    #pragma unroll
    for(int i=0;i<2;++i){
      const int tok=16*(tbase+i)+l16;
      u16x4 pq,pk,pv;
      #pragma unroll
      for(int r=0;r<4;++r){
        pq[r]=f2b(qa[i][r]+bq4[r]);
        pk[r]=f2b(ka[i][r]+bk4[r]);
        pv[r]=f2b(va[i][r]+bv);
      }
      *(u16x4*)(sm+qp_off(RQ_B,tok,32*ct+8*lg))=pq;                  // Q[tok][qch]
      *(u16x4*)(sm+qp_off(RK_B,tok,32*ct+8*lg))=pk;                  // K[tok][qch]
      *(u16x4*)(sm+vt_off(ct*16+l16,(16*(tbase+i)+4*lg)*2))=pv;      // VT[vch][tok]
    }
  };

  c1(0);
  __syncthreads();

  const float SM_C = 0.25503487f;  // log2(e)/sqrt(32), applied in f32 at exp2
  #pragma unroll 1
  for(int h=0;h<6;++h){
    // ---- S^T = K.Q (A=K rows=ktok, B=Q col=own q) ; softmax in-register ----
    {
      const int q=16*w+l16;
      const bf16x8 bqf=*(const bf16x8*)(sm+qp_off(RQ_B,q,lg*16));
      f32x4 sv[4];
      #pragma unroll
      for(int kt=0;kt<4;++kt){
        const bf16x8 akf=*(const bf16x8*)(sm+qp_off(RK_B,16*kt+l16,lg*16));
        sv[kt]=__builtin_amdgcn_mfma_f32_16x16x32_bf16(akf,bqf,(f32x4){0,0,0,0},0,0,0);
      }
      float mx=-3.0e38f;
      #pragma unroll
      for(int kt=0;kt<4;++kt){
        #pragma unroll
        for(int r=0;r<4;++r) mx=fmaxf(mx,sv[kt][r]);
      }
      mx=fmaxf(mx,__shfl_xor(mx,16)); mx=fmaxf(mx,__shfl_xor(mx,32));
      float sum=0.f;
      #pragma unroll
      for(int kt=0;kt<4;++kt){
        #pragma unroll
        for(int r=0;r<4;++r){ float e=exp2f((sv[kt][r]-mx)*SM_C); sv[kt][r]=e; sum+=e; }
      }
      sum+=__shfl_xor(sum,16); sum+=__shfl_xor(sum,32);
      const float rs=1.f/sum;
      U64 pk0,pk1,pk2,pk3;
      #pragma unroll
      for(int r=0;r<4;++r){ pk0.v[r]=f2b(sv[0][r]*rs); pk1.v[r]=f2b(sv[1][r]*rs);
                            pk2.v[r]=f2b(sv[2][r]*rs); pk3.v[r]=f2b(sv[3][r]*rs); }
      const int srcA = ((lg&1)<<5) + l16, srcB = srcA + 16;
      unsigned long long rA0=__shfl(pk0.u,srcA), rB0=__shfl(pk0.u,srcB);
      unsigned long long rA1=__shfl(pk1.u,srcA), rB1=__shfl(pk1.u,srcB);
      unsigned long long rA2=__shfl(pk2.u,srcA), rB2=__shfl(pk2.u,srcB);
      unsigned long long rA3=__shfl(pk3.u,srcA), rB3=__shfl(pk3.u,srcB);
      U128 pf0, pf1;
      pf0.q[0]=(lg<2)?rA0:rA1;  pf0.q[1]=(lg<2)?rB0:rB1;   // ktok 0..31
      pf1.q[0]=(lg<2)?rA2:rA3;  pf1.q[1]=(lg<2)?rB2:rB3;   // ktok 32..63
      // ---- PV: A=VT (rows d), B=P (col=own q) -> D[d][q]; write O[q][d] ----
      f32x4 ov[2]={(f32x4){0,0,0,0},(f32x4){0,0,0,0}};
      #pragma unroll
      for(int dt=0;dt<2;++dt){
        const bf16x8 av0=*(const bf16x8*)(sm+vt_off(16*dt+l16,lg*16));
        const bf16x8 av1=*(const bf16x8*)(sm+vt_off(16*dt+l16,64+lg*16));
        ov[dt]=__builtin_amdgcn_mfma_f32_16x16x32_bf16(av0,pf0.b,ov[dt],0,0,0);
        ov[dt]=__builtin_amdgcn_mfma_f32_16x16x32_bf16(av1,pf1.b,ov[dt],0,0,0);
      }
      #pragma unroll
      for(int dt=0;dt<2;++dt){
        u16x4 po;
        #pragma unroll
        for(int r=0;r<4;++r) po[r]=f2b(ov[dt][r]);
        *(u16x4*)(sm+qp_off(RO_B,q,32*dt+8*lg))=po;   // own q row
      }
    }
    __syncthreads();   // O visible; Q/K/VT reads done
    // ---- proj accumulate directly into t: A=Wproj rows=own outch, B=O col=tok ----
    {
      bf16x8 bo[4];
      #pragma unroll
      for(int tt=0;tt<4;++tt) bo[tt]=*(const bf16x8*)(sm+qp_off(RO_B,16*tt+l16,lg*16));
      #pragma unroll
      for(int mt=0;mt<3;++mt){
        const bf16x8 aw=*(const bf16x8*)(wprojT+(16*(3*w+mt)+l16)*192+h*32+lg*8);
        #pragma unroll
        for(int tt=0;tt<4;++tt)
          t[mt][tt]=__builtin_amdgcn_mfma_f32_16x16x32_bf16(aw,bo[tt],t[mt][tt],0,0,0);
      }
    }
    if(h<5){ c1(h+1); __syncthreads(); }
  }

  // ---- proj bias once ----
  #pragma unroll
  for(int mt=0;mt<3;++mt){
    const f32x4 bp=*(const f32x4*)(bproj+48*w+16*mt+4*lg);
    #pragma unroll
    for(int tt=0;tt<4;++tt) t[mt][tt]+=bp;
  }

  // ---- LN2 (red overlays RQ; all Q reads finished) ----
  layernorm(ln2g, ln2b);
  __syncthreads();   // h2 visible; attn buffers dead -> G area free

  // ---- MLP: 6 chunks of 128 mch; MLP2 accumulates into t ----
  #pragma unroll 1
  for(int qc=0;qc<6;++qc){
    f32x4 g[2][4];
    #pragma unroll
    for(int m=0;m<2;++m)
      #pragma unroll
      for(int tt=0;tt<4;++tt) g[m][tt]=(f32x4){0,0,0,0};
    #pragma unroll
    for(int ks=0;ks<6;++ks){
      bf16x8 bh2[4];
      #pragma unroll
      for(int tt=0;tt<4;++tt) bh2[tt]=*(const bf16x8*)(sm+sa_off(16*tt+l16,ks*64+lg*16));
      #pragma unroll
      for(int m=0;m<2;++m){
        const bf16x8 aw=*(const bf16x8*)(wmlp1T+(qc*128+16*(2*w+m)+l16)*192+ks*32+lg*8);
        #pragma unroll
        for(int tt=0;tt<4;++tt)
          g[m][tt]=__builtin_amdgcn_mfma_f32_16x16x32_bf16(aw,bh2[tt],g[m][tt],0,0,0);
      }
    }
    #pragma unroll
    for(int m=0;m<2;++m){
      const f32x4 b1=*(const f32x4*)(bmlp1+qc*128+16*(2*w+m)+4*lg);
      #pragma unroll
      for(int tt=0;tt<4;++tt){
        u16x4 pg;
        #pragma unroll
        for(int r=0;r<4;++r){
          const float xv=g[m][tt][r]+b1[r];
          // gelu(x) ~= x * sigmoid(1.702 x); |err|<=~0.01, contributes <~1e-3 after W2
          const float e=exp2f(-2.4554664f*xv);
          pg[r]=f2b(xv*__builtin_amdgcn_rcpf(1.f+e));
        }
        *(u16x4*)(sm+g_off(16*tt+l16,(16*(2*w+m)+4*lg)*2))=pg;  // G[tok][mch]
      }
    }
    __syncthreads();   // G visible
    #pragma unroll
    for(int ks2=0;ks2<4;++ks2){
      bf16x8 bg[4];
      #pragma unroll
      for(int tt=0;tt<4;++tt) bg[tt]=*(const bf16x8*)(sm+g_off(16*tt+l16,ks2*64+lg*16));
      #pragma unroll
      for(int mt=0;mt<3;++mt){
        const bf16x8 aw2=*(const bf16x8*)(wmlp2T+(16*(3*w+mt)+l16)*768+qc*128+ks2*32+lg*8);
        #pragma unroll
        for(int tt=0;tt<4;++tt)
          t[mt][tt]=__builtin_amdgcn_mfma_f32_16x16x32_bf16(aw2,bg[tt],t[mt][tt],0,0,0);
      }
    }
    if(qc<5) __syncthreads();  // WAR before next G write
  }

  // ---- Final: out = t + bmlp2 ----
  if(MODE==1){
    float* outp=(float*)outp_;
    const int bb=wid>>10, wh=(wid>>5)&31, wwi=wid&31;
    const size_t imgoff=(size_t)bb*192*65536 + (size_t)(wh*8)*256 + (size_t)(wwi*8);
    #pragma unroll
    for(int mt=0;mt<3;++mt){
      const f32x4 b2=*(const f32x4*)(bmlp2+48*w+16*mt+4*lg);
      #pragma unroll
      for(int tt=0;tt<4;++tt){
        const int T=16*tt+l16, tp=(T>>3)*256+(T&7);
        #pragma unroll
        for(int r=0;r<4;++r)
          outp[imgoff+(size_t)(48*w+16*mt+4*lg+r)*65536+tp]=t[mt][tt][r]+b2[r];
      }
    }
  } else {
    unsigned short* rwh=(unsigned short*)outp_;
    #pragma unroll
    for(int mt=0;mt<3;++mt){
      const f32x4 b2=*(const f32x4*)(bmlp2+48*w+16*mt+4*lg);
      #pragma unroll
      for(int tt=0;tt<4;++tt){
        u16x4 po;
        #pragma unroll
        for(int r=0;r<4;++r) po[r]=f2b(t[mt][tt][r]+b2[r]);
        *(u16x4*)(rwh + ((size_t)(wid*48 + 12*w+4*mt+lg)*64 + 16*tt+l16)*4)=po;
      }
    }
  }
}

extern "C" void kernel_launch(void* const* d_in, const int* in_sizes, int n_in,
                              void* d_out, int out_size, void* d_ws, size_t ws_size,
                              hipStream_t stream) {
  const float* x      = (const float*)d_in[0];
  const float* w_qkv  = (const float*)d_in[1];
  const float* b_qkv  = (const float*)d_in[2];
  const float* w_proj = (const float*)d_in[3];
  const float* b_proj = (const float*)d_in[4];
  const float* ln1g   = (const float*)d_in[5];
  const float* ln1b   = (const float*)d_in[6];
  const float* ln2g   = (const float*)d_in[7];
  const float* ln2b   = (const float*)d_in[8];
  const float* w_mlp1 = (const float*)d_in[9];
  const float* b_mlp1 = (const float*)d_in[10];
  const float* w_mlp2 = (const float*)d_in[11];
  const float* b_mlp2 = (const float*)d_in[12];
  float* out = (float*)d_out;
  unsigned short* wsu = (unsigned short*)d_ws;

  prep_weights<<<dim3(1728), dim3(256), 0, stream>>>(w_qkv, w_proj, w_mlp1, w_mlp2, wsu);

  const size_t OFF = 1ull<<20;
  const size_t avail = ws_size > OFF ? ws_size - OFF : 0;
  int nchunks = 0;
  if      (avail >= 4096ull*24576ull) nchunks = 1;
  else if (avail >= 2048ull*24576ull) nchunks = 2;
  else if (avail >= 1024ull*24576ull) nchunks = 4;
  else if (avail >=  512ull*24576ull) nchunks = 8;

  if (nchunks){
    unsigned short* xwh = (unsigned short*)((char*)d_ws + OFF);
    const int nw = 4096/nchunks;          // windows per chunk (multiple of 512)
    for (int c=0;c<nchunks;++c){
      const int w0 = c*nw, r0 = w0>>5;    // window-row base
      relayout_in<<<dim3(nw/4), dim3(256), 0, stream>>>(x, xwh, r0);
      winblock<2><<<dim3(nw), dim3(256), 0, stream>>>(
          (const void*)xwh, (void*)xwh, b_qkv, b_proj, ln1g, ln1b, ln2g, ln2b, b_mlp1, b_mlp2,
          wsu, wsu+110592, wsu+147456, wsu+294912);
      relayout_out<<<dim3(nw/4), dim3(256), 0, stream>>>(xwh, out, r0);
    }
  } else {
    winblock<1><<<dim3(4096), dim3(256), 0, stream>>>(
        (const void*)x, (void*)out, b_qkv, b_proj, ln1g, ln1b, ln2g, ln2b, b_mlp1, b_mlp2,
        wsu, wsu+110592, wsu+147456, wsu+294912);
  }
}